// Round 4
// baseline (356.403 us; speedup 1.0000x reference)
//
#include <hip/hip_runtime.h>

#define BB 128
#define CC 272
#define TT 1024
#define DD 270
#define KK 32
#define NKC 9              // k-chunks of 32 (C padded to 288)
#define NMT 17             // d-tiles of 16 (D padded to 272)
#define MP 272

typedef __attribute__((ext_vector_type(8))) short s16x8;
typedef __attribute__((ext_vector_type(4))) float f32x4;

__device__ __forceinline__ unsigned short f2bf(float f) {
  unsigned int u = __builtin_bit_cast(unsigned int, f);
  u += 0x7fffu + ((u >> 16) & 1u);   // round-to-nearest-even
  return (unsigned short)(u >> 16);
}

// ---------------- Kernel 1: partial A[d][c], 4-way k-split ----------------
__global__ __launch_bounds__(288) void phaseA_kernel(
    const float* __restrict__ loc, const float* __restrict__ z_re,
    const float* __restrict__ z_im, float* __restrict__ A) {
  const int d = blockIdx.x;
  const int p = blockIdx.y;          // k-part 0..3
  const int c = threadIdx.x;
  if (c >= CC) return;
  const float TWO_PI = 6.28318530717958647692f;
  float x = loc[2 * c], y = loc[2 * c + 1];
  float sx, cx, sy, cyv;
  sincosf(TWO_PI * x, &sx, &cx);
  sincosf(TWO_PI * y, &sy, &cyv);
  float cl[KK], sl[KK];
  cl[0] = 1.f; sl[0] = 0.f;
#pragma unroll
  for (int l = 1; l < KK; ++l) {
    cl[l] = cl[l - 1] * cyv - sl[l - 1] * sy;
    sl[l] = sl[l - 1] * cyv + cl[l - 1] * sy;
  }
  const int k0 = p * 8;
  float sk, ck;
  sincosf(TWO_PI * (float)k0 * x, &sk, &ck);
  const float* zr = z_re + (size_t)d * (KK * KK) + k0 * KK;
  const float* zi = z_im + (size_t)d * (KK * KK) + k0 * KK;
  float acc = 0.f;
  for (int k = 0; k < 8; ++k) {
    float s_rc = 0.f, s_rs = 0.f, s_ic = 0.f, s_is = 0.f;
#pragma unroll
    for (int l = 0; l < KK; ++l) {
      float vr = zr[k * KK + l];   // wave-uniform -> scalar loads
      float vi = zi[k * KK + l];
      s_rc += vr * cl[l];
      s_rs += vr * sl[l];
      s_ic += vi * cl[l];
      s_is += vi * sl[l];
    }
    acc += ck * (s_rc + s_is) + sk * (s_ic - s_rs);
    float nck = ck * cx - sk * sx;
    sk = sk * cx + ck * sx;
    ck = nck;
  }
  atomicAdd(&A[d * CC + c], acc);
}

// ---------------- Kernel 2: row softmax -> bf16 w, MFMA-fragment layout ---
// Frag (kc, mt) = 1024 B: lane l = hi*16 + m holds w[mt*16+m][kc*32+hi*8+j],
// j=0..7 — the A-operand layout of mfma_f32_16x16x32_bf16 (verified in
// rounds 0-2). GEMM reads each frag as ONE coalesced 1 KB dwordx4/wave.
// Rows d>=270 and cols c>=272 are zeros (M/K padding).
__global__ __launch_bounds__(64) void softmax_kernel(
    const float* __restrict__ A, unsigned short* __restrict__ wb) {
  const int d = blockIdx.x;   // 0..271
  const int lane = threadIdx.x;
  const bool live = (d < DD);
  float v[5];
  float inv = 0.f;
  if (live) {
    float m = -3.0e38f;
#pragma unroll
    for (int j = 0; j < 5; ++j) {
      int cidx = lane + 64 * j;
      v[j] = (cidx < CC) ? A[(size_t)d * CC + cidx] : -3.0e38f;
      m = fmaxf(m, v[j]);
    }
#pragma unroll
    for (int off = 32; off >= 1; off >>= 1) m = fmaxf(m, __shfl_xor(m, off, 64));
    float s = 0.f;
#pragma unroll
    for (int j = 0; j < 5; ++j) {
      int cidx = lane + 64 * j;
      v[j] = (cidx < CC) ? expf(v[j] - m) : 0.f;
      s += v[j];
    }
#pragma unroll
    for (int off = 32; off >= 1; off >>= 1) s += __shfl_xor(s, off, 64);
    inv = 1.f / s;
  }
  const int mt = d >> 4, mrow = d & 15;
#pragma unroll
  for (int j = 0; j < 5; ++j) {
    int kk = lane + 64 * j;      // column index incl. padding
    if (kk < NKC * KK) {
      unsigned short val = 0;
      if (live && kk < CC) val = f2bf(v[j] * inv);
      int kc = kk >> 5, hi = (kk >> 3) & 3, jj = kk & 7;
      wb[((size_t)(kc * NMT + mt) << 9) + (((hi << 4) | mrow) << 3) + jj] = val;
    }
  }
}

// ---------------- Kernel 3: out[b,d,t] = sum_c w[d,c] * X[b,c,t] ----------
// 256 threads = 4 INDEPENDENT waves (no LDS, no barriers). Block covers
// (b, 32-t tile). Each wave computes m-tiles {dw, dw+4, dw+8, dw+12, 16}
// (tile 16 computed by all for uniform code; stored only by wave 0).
// acc = 5 x 2 x f32x4 = 40 regs. X: 16 floats/chunk/lane, register ring
// 3 chunks deep (issue-to-use ~ 2 full bodies). A-frags: 1 KB coalesced
// dwordx4 from the L2-resident w, 1-chunk prefetch. Depth x waves gives
// >= 64 KB of in-flight loads per CU (vs ~8 KB in rounds 0-2), covering
// the ~900-cycle HBM latency: BW = inflight/latency, not wave count.
__global__ __launch_bounds__(256, 2) void gemm_kernel(
    const float* __restrict__ X, const unsigned short* __restrict__ wb,
    float* __restrict__ out) {
  const int bid = blockIdx.x;
  const int b = bid >> 5;
  const int t0 = (bid & 31) << 5;     // 32-wide t tile
  const int tid = threadIdx.x;
  const int lane = tid & 63;
  const int dw = tid >> 6;            // d-group 0..3 (wave-uniform)
  const int q = lane >> 4;            // k-subgroup 0..3
  const int r16 = lane & 15;
  const int csub = q << 3;

  const unsigned short* wfl = wb + (size_t)lane * 8;
  const float* Xb = X + (size_t)b * (CC * TT) + t0 + r16;

  f32x4 acc[5][2];
#pragma unroll
  for (int i = 0; i < 5; ++i)
#pragma unroll
    for (int f = 0; f < 2; ++f) acc[i][f] = (f32x4){0.f, 0.f, 0.f, 0.f};

#define MTI(I) ((I) < 4 ? dw + 4 * (I) : 16)
#define ALOAD(KC, I) (*(const s16x8*)(wfl + ((size_t)((KC) * NMT + MTI(I)) << 9)))
// DST[j] = frag0 elem j (t = r16), DST[8+j] = frag1 elem j (t = r16+16)
#define XLOAD(DST, KC)                                                  \
  {                                                                     \
    _Pragma("unroll") for (int j = 0; j < 8; ++j) {                     \
      int c_ = (KC) * KK + csub + j;                                    \
      float v0_ = 0.f, v1_ = 0.f;                                       \
      if ((KC) < 8 || c_ < CC) {                                        \
        v0_ = Xb[(size_t)c_ * TT];                                      \
        v1_ = Xb[(size_t)c_ * TT + 16];                                 \
      }                                                                 \
      DST[j] = v0_;                                                     \
      DST[8 + j] = v1_;                                                 \
    }                                                                   \
  }

  s16x8 ac[5], an[5];
  float x0[16], x1[16], x2[16];

  // ---- prologue: 3-deep X, 1-deep A ----
  XLOAD(x0, 0);
  XLOAD(x1, 1);
  XLOAD(x2, 2);
#pragma unroll
  for (int i = 0; i < 5; ++i) ac[i] = ALOAD(0, i);

#define BODY(KC, XC)                                                          \
  {                                                                           \
    if ((KC) + 1 < NKC) {                                                     \
      _Pragma("unroll") for (int i = 0; i < 5; ++i) an[i] = ALOAD((KC) + 1, i); \
    }                                                                         \
    union { unsigned int u[4]; s16x8 v; } bf[2];                              \
    _Pragma("unroll") for (int f = 0; f < 2; ++f)                             \
        _Pragma("unroll") for (int p = 0; p < 4; ++p)                         \
        bf[f].u[p] = (unsigned int)f2bf(XC[f * 8 + 2 * p]) |                  \
                     ((unsigned int)f2bf(XC[f * 8 + 2 * p + 1]) << 16);       \
    if ((KC) + 3 < NKC) { XLOAD(XC, (KC) + 3); }                              \
    _Pragma("unroll") for (int i = 0; i < 5; ++i)                             \
        _Pragma("unroll") for (int f = 0; f < 2; ++f)                         \
        acc[i][f] = __builtin_amdgcn_mfma_f32_16x16x32_bf16(ac[i], bf[f].v,   \
                                                            acc[i][f], 0, 0, 0); \
    if ((KC) + 1 < NKC) {                                                     \
      _Pragma("unroll") for (int i = 0; i < 5; ++i) ac[i] = an[i];            \
    }                                                                         \
  }

  BODY(0, x0) BODY(1, x1) BODY(2, x2)
  BODY(3, x0) BODY(4, x1) BODY(5, x2)
  BODY(6, x0) BODY(7, x1) BODY(8, x2)

#undef BODY
#undef XLOAD
#undef ALOAD
#undef MTI

  // ---- epilogue: D row = mt*16 + q*4 + r, col t = t0 + f*16 + r16 ----
  float* op = out + (size_t)b * (DD * TT) + t0 + r16;
#pragma unroll
  for (int i = 0; i < 4; ++i) {
    const int mtb = (dw + (i << 2)) << 4;   // <= 240; +15 < DD always
#pragma unroll
    for (int f = 0; f < 2; ++f)
#pragma unroll
      for (int r = 0; r < 4; ++r)
        op[(size_t)(mtb + q * 4 + r) * TT + (f << 4)] = acc[i][f][r];
  }
  if (dw == 0) {
#pragma unroll
    for (int f = 0; f < 2; ++f)
#pragma unroll
      for (int r = 0; r < 4; ++r) {
        const int drow = 256 + q * 4 + r;
        if (drow < DD) op[(size_t)drow * TT + (f << 4)] = acc[4][f][r];
      }
  }
}

extern "C" void kernel_launch(void* const* d_in, const int* in_sizes, int n_in,
                              void* d_out, int out_size, void* d_ws, size_t ws_size,
                              hipStream_t stream) {
  const float* X = (const float*)d_in[0];
  const float* loc = (const float*)d_in[1];
  const float* z_re = (const float*)d_in[2];
  const float* z_im = (const float*)d_in[3];
  float* out = (float*)d_out;

  float* A = (float*)d_ws;                                        // 293,760 B
  unsigned short* wbf = (unsigned short*)((char*)d_ws + 294912);  // 156,672 B

  hipMemsetAsync(A, 0, DD * CC * sizeof(float), stream);
  phaseA_kernel<<<dim3(DD, 4), 288, 0, stream>>>(loc, z_re, z_im, A);
  softmax_kernel<<<MP, 64, 0, stream>>>(A, wbf);
  gemm_kernel<<<BB * (TT / 32), 256, 0, stream>>>(X, wbf, out);
}

// Round 5
// 309.132 us; speedup vs baseline: 1.1529x; 1.1529x over previous
//
#include <hip/hip_runtime.h>

#define BB 128
#define CC 272
#define TT 1024
#define DD 270
#define KK 32
#define NKC 9              // k-chunks of 32 (C padded to 288)
#define NMT 17             // d-tiles of 16 (D padded to 272)
#define MP 272
#define WUNITS ((NKC * NMT * 1024) / 16)   // 9792 16B units = 156,672 B

typedef __attribute__((ext_vector_type(8))) short s16x8;
typedef __attribute__((ext_vector_type(4))) float f32x4;

__device__ __forceinline__ unsigned short f2bf(float f) {
  unsigned int u = __builtin_bit_cast(unsigned int, f);
  u += 0x7fffu + ((u >> 16) & 1u);   // round-to-nearest-even
  return (unsigned short)(u >> 16);
}

// ---------------- Kernel 1: partial A[d][c], 4-way k-split ----------------
__global__ __launch_bounds__(288) void phaseA_kernel(
    const float* __restrict__ loc, const float* __restrict__ z_re,
    const float* __restrict__ z_im, float* __restrict__ A) {
  const int d = blockIdx.x;
  const int p = blockIdx.y;          // k-part 0..3
  const int c = threadIdx.x;
  if (c >= CC) return;
  const float TWO_PI = 6.28318530717958647692f;
  float x = loc[2 * c], y = loc[2 * c + 1];
  float sx, cx, sy, cyv;
  sincosf(TWO_PI * x, &sx, &cx);
  sincosf(TWO_PI * y, &sy, &cyv);
  float cl[KK], sl[KK];
  cl[0] = 1.f; sl[0] = 0.f;
#pragma unroll
  for (int l = 1; l < KK; ++l) {
    cl[l] = cl[l - 1] * cyv - sl[l - 1] * sy;
    sl[l] = sl[l - 1] * cyv + cl[l - 1] * sy;
  }
  const int k0 = p * 8;
  float sk, ck;
  sincosf(TWO_PI * (float)k0 * x, &sk, &ck);
  const float* zr = z_re + (size_t)d * (KK * KK) + k0 * KK;
  const float* zi = z_im + (size_t)d * (KK * KK) + k0 * KK;
  float acc = 0.f;
  for (int k = 0; k < 8; ++k) {
    float s_rc = 0.f, s_rs = 0.f, s_ic = 0.f, s_is = 0.f;
#pragma unroll
    for (int l = 0; l < KK; ++l) {
      float vr = zr[k * KK + l];   // wave-uniform -> scalar loads
      float vi = zi[k * KK + l];
      s_rc += vr * cl[l];
      s_rs += vr * sl[l];
      s_ic += vi * cl[l];
      s_is += vi * sl[l];
    }
    acc += ck * (s_rc + s_is) + sk * (s_ic - s_rs);
    float nck = ck * cx - sk * sx;
    sk = sk * cx + ck * sx;
    ck = nck;
  }
  atomicAdd(&A[d * CC + c], acc);
}

// ---------------- Kernel 2: row softmax -> bf16 w, MFMA-fragment layout ---
// Frag (kc, mt) = 1024 B: lane l = hi*16 + m holds w[mt*16+m][kc*32+hi*8+j],
// j=0..7 — the A-operand layout of mfma_f32_16x16x32_bf16 (harness-verified
// rounds 0-2,4). Frags stored contiguously: GEMM stages the buffer as a flat
// memcpy into LDS and reads each frag as ds_read_b128 at base + lane*16 —
// lane-sequential 16 B = bank-conflict-free. Pads (d>=270, c>=272) are zero.
__global__ __launch_bounds__(64) void softmax_kernel(
    const float* __restrict__ A, unsigned short* __restrict__ wb) {
  const int d = blockIdx.x;   // 0..271
  const int lane = threadIdx.x;
  const bool live = (d < DD);
  float v[5];
  float inv = 0.f;
  if (live) {
    float m = -3.0e38f;
#pragma unroll
    for (int j = 0; j < 5; ++j) {
      int cidx = lane + 64 * j;
      v[j] = (cidx < CC) ? A[(size_t)d * CC + cidx] : -3.0e38f;
      m = fmaxf(m, v[j]);
    }
#pragma unroll
    for (int off = 32; off >= 1; off >>= 1) m = fmaxf(m, __shfl_xor(m, off, 64));
    float s = 0.f;
#pragma unroll
    for (int j = 0; j < 5; ++j) {
      int cidx = lane + 64 * j;
      v[j] = (cidx < CC) ? expf(v[j] - m) : 0.f;
      s += v[j];
    }
#pragma unroll
    for (int off = 32; off >= 1; off >>= 1) s += __shfl_xor(s, off, 64);
    inv = 1.f / s;
  }
  const int mt = d >> 4, mrow = d & 15;
#pragma unroll
  for (int j = 0; j < 5; ++j) {
    int kk = lane + 64 * j;      // column index incl. padding
    if (kk < NKC * KK) {
      unsigned short val = 0;
      if (live && kk < CC) val = f2bf(v[j] * inv);
      int kc = kk >> 5, hi = (kk >> 3) & 3, jj = kk & 7;
      wb[((size_t)(kc * NMT + mt) << 9) + (((hi << 4) | mrow) << 3) + jj] = val;
    }
  }
}

// ---------------- Kernel 3: out[b,d,t] = sum_c w[d,c] * X[b,c,t] ----------
// Round-0 platform (best measured: 89.6 us) with its two measured losses
// fixed. 512 threads = 8 waves; block = (b, 256-t tile); wave wv owns
// t in [t0+32*wv, +32) -> 2 B-frags, so each A-frag ds_read feeds 2 MFMAs
// (halves LDS-port time vs round 0). Whole w staged ONCE into LDS as a flat
// memcpy (layout already frag-linear): A-read = ds_read_b128 at
// frag_base + lane*16 -> conflict-free (round 0 had 5M conflict cycles).
// X: 3-deep register prefetch, no barriers after the single staging sync.
// XCD-swizzled bid: all 4 t-tiles of a b on one XCD (512%8==0, bijective).
__global__ __launch_bounds__(512, 2) void gemm_kernel(
    const float* __restrict__ X, const unsigned short* __restrict__ wb,
    float* __restrict__ out) {
  __shared__ unsigned short wlds[NKC * NMT * 512];   // 156,672 B
  const int bid = blockIdx.x;
  const int L = (bid & 7) * 64 + (bid >> 3);   // de-swizzle: XCD gets 64 consecutive L
  const int b = L >> 2;
  const int t0 = (L & 3) << 8;                 // 256-wide t tile
  const int tid = threadIdx.x;
  const int lane = tid & 63;
  const int wv = tid >> 6;            // 0..7
  const int q = lane >> 4;            // k-subgroup 0..3
  const int r16 = lane & 15;
  const int csub = q << 3;

  // ---- stage all of w: 9792 x 16B over 512 threads (20 rounds) ----
  {
    const char* src = (const char*)wb;
    char* dst = (char*)wlds;
#pragma unroll
    for (int r = 0; r < 20; ++r) {
      int idx = tid + r * 512;
      if (idx < WUNITS) {
        __builtin_amdgcn_global_load_lds(
            (const __attribute__((address_space(1))) unsigned int*)(src + idx * 16),
            (__attribute__((address_space(3))) unsigned int*)(dst + idx * 16),
            16, 0, 0);
      }
    }
  }

  f32x4 acc[NMT][2];
#pragma unroll
  for (int i = 0; i < NMT; ++i)
#pragma unroll
    for (int f = 0; f < 2; ++f) acc[i][f] = (f32x4){0.f, 0.f, 0.f, 0.f};

  const float* Xb = X + (size_t)b * (CC * TT) + t0 + wv * 32 + r16;

// DST[j] = frag0 elem j (t offset 0), DST[8+j] = frag1 elem j (t offset 16)
#define XLOAD(DST, KC)                                                  \
  {                                                                     \
    _Pragma("unroll") for (int j = 0; j < 8; ++j) {                     \
      int c_ = (KC) * KK + csub + j;                                    \
      float v0_ = 0.f, v1_ = 0.f;                                       \
      if ((KC) < 8 || c_ < CC) {                                        \
        v0_ = Xb[(size_t)c_ * TT];                                      \
        v1_ = Xb[(size_t)c_ * TT + 16];                                 \
      }                                                                 \
      DST[j] = v0_;                                                     \
      DST[8 + j] = v1_;                                                 \
    }                                                                   \
  }

  float x0[16], x1[16], x2[16];
  XLOAD(x0, 0);
  XLOAD(x1, 1);
  XLOAD(x2, 2);

  __syncthreads();   // single barrier: w staged (drains vmcnt once)

#define BODY(KC, XC)                                                          \
  {                                                                           \
    union { unsigned int u[4]; s16x8 v; } bf[2];                              \
    _Pragma("unroll") for (int f = 0; f < 2; ++f)                             \
        _Pragma("unroll") for (int p = 0; p < 4; ++p)                         \
        bf[f].u[p] = (unsigned int)f2bf(XC[f * 8 + 2 * p]) |                  \
                     ((unsigned int)f2bf(XC[f * 8 + 2 * p + 1]) << 16);       \
    if ((KC) + 3 < NKC) { XLOAD(XC, (KC) + 3); }                              \
    const char* wch_ = (const char*)wlds + (size_t)(KC) * (NMT * 1024) +      \
                       (size_t)lane * 16;                                     \
    _Pragma("unroll") for (int mt = 0; mt < NMT; ++mt) {                      \
      s16x8 af_ = *(const s16x8*)(wch_ + mt * 1024);                          \
      acc[mt][0] = __builtin_amdgcn_mfma_f32_16x16x32_bf16(af_, bf[0].v,      \
                                                           acc[mt][0], 0, 0, 0); \
      acc[mt][1] = __builtin_amdgcn_mfma_f32_16x16x32_bf16(af_, bf[1].v,      \
                                                           acc[mt][1], 0, 0, 0); \
    }                                                                         \
  }

  BODY(0, x0) BODY(1, x1) BODY(2, x2)
  BODY(3, x0) BODY(4, x1) BODY(5, x2)
  BODY(6, x0) BODY(7, x1) BODY(8, x2)

#undef BODY
#undef XLOAD

  // ---- epilogue: D row = mt*16 + q*4 + r, col t = t0 + wv*32 + f*16 + r16 --
  float* op = out + (size_t)b * (DD * TT) + t0 + wv * 32 + r16;
#pragma unroll
  for (int mt = 0; mt < NMT; ++mt) {
#pragma unroll
    for (int f = 0; f < 2; ++f)
#pragma unroll
      for (int r = 0; r < 4; ++r) {
        const int drow = mt * 16 + q * 4 + r;
        if (drow < DD) op[(size_t)drow * TT + (f << 4)] = acc[mt][f][r];
      }
  }
}

extern "C" void kernel_launch(void* const* d_in, const int* in_sizes, int n_in,
                              void* d_out, int out_size, void* d_ws, size_t ws_size,
                              hipStream_t stream) {
  const float* X = (const float*)d_in[0];
  const float* loc = (const float*)d_in[1];
  const float* z_re = (const float*)d_in[2];
  const float* z_im = (const float*)d_in[3];
  float* out = (float*)d_out;

  float* A = (float*)d_ws;                                        // 293,760 B
  unsigned short* wbf = (unsigned short*)((char*)d_ws + 294912);  // 156,672 B

  hipMemsetAsync(A, 0, DD * CC * sizeof(float), stream);
  phaseA_kernel<<<dim3(DD, 4), 288, 0, stream>>>(loc, z_re, z_im, A);
  softmax_kernel<<<MP, 64, 0, stream>>>(A, wbf);
  gemm_kernel<<<BB * (TT / 256), 512, 0, stream>>>(X, wbf, out);
}